// Round 5
// baseline (292.469 us; speedup 1.0000x reference)
//
#include <hip/hip_runtime.h>
#include <math.h>

#define B_ 32
#define S_ 1024
#define H_ 512
#define K_ 1024                 // 2*H
#define M_ (B_ * S_)            // 32768

typedef __attribute__((ext_vector_type(8))) short bf16x8;
typedef __attribute__((ext_vector_type(16))) float f32x16;

// Round-half-up split: f = hi + lo.  Residual r = f - fh is EXACT regardless
// of hi's rounding mode, so half-up matches RNE accuracy (total error =
// lo rounding <= 2^-18 rel).
__device__ __forceinline__ void split_bf16(float f, unsigned short& hi, unsigned short& lo) {
    unsigned u = __float_as_uint(f);
    unsigned r = u + 0x8000u;
    hi = (unsigned short)(r >> 16);
    float fh = __uint_as_float(r & 0xffff0000u);
    float res = f - fh;
    lo = (unsigned short)((__float_as_uint(res) + 0x8000u) >> 16);
}

// split 8 floats -> two 16B LDS stores; v_perm packs 2 halves/op.
__device__ __forceinline__ void split8_store(const float4& x, const float4& y,
                                             unsigned short* hiP, unsigned short* loP) {
    float f[8] = {x.x, x.y, x.z, x.w, y.x, y.y, y.z, y.w};
    unsigned hr[8], lr[8];
    #pragma unroll
    for (int i = 0; i < 8; ++i) {
        unsigned u = __float_as_uint(f[i]);
        unsigned r = u + 0x8000u;
        hr[i] = r;
        float fh = __uint_as_float(r & 0xffff0000u);
        lr[i] = __float_as_uint(f[i] - fh) + 0x8000u;
    }
    uint4 Hv, Lv;
    Hv.x = __builtin_amdgcn_perm(hr[1], hr[0], 0x07060302u);
    Hv.y = __builtin_amdgcn_perm(hr[3], hr[2], 0x07060302u);
    Hv.z = __builtin_amdgcn_perm(hr[5], hr[4], 0x07060302u);
    Hv.w = __builtin_amdgcn_perm(hr[7], hr[6], 0x07060302u);
    Lv.x = __builtin_amdgcn_perm(lr[1], lr[0], 0x07060302u);
    Lv.y = __builtin_amdgcn_perm(lr[3], lr[2], 0x07060302u);
    Lv.z = __builtin_amdgcn_perm(lr[5], lr[4], 0x07060302u);
    Lv.w = __builtin_amdgcn_perm(lr[7], lr[6], 0x07060302u);
    *reinterpret_cast<uint4*>(hiP) = Hv;
    *reinterpret_cast<uint4*>(loP) = Lv;
}

// tanh via HW exp + rcp: (e^2x - 1)/(e^2x + 1).  ~8 ops, |err| ~1e-6.
__device__ __forceinline__ float fast_tanh(float x) {
    float xc = fminf(fmaxf(x, -15.f), 15.f);
    float t = __expf(2.0f * xc);
    return (t - 1.0f) * __builtin_amdgcn_rcpf(t + 1.0f);
}

// async 16B global -> LDS (lane i lands at lds_base + i*16; lds_base wave-uniform)
__device__ __forceinline__ void async_copy16(const void* g, void* l) {
    __builtin_amdgcn_global_load_lds(
        (const __attribute__((address_space(1))) void*)g,
        (__attribute__((address_space(3))) void*)l, 16, 0, 0);
}

// ---------------------------------------------------------------------------
// Kernel 1: merged prep.
//   blocks [0,256):  hb[b][h] = sum_k hidden[b][k]*W[k][h] + bias[h]
//   blocks [256,768): transpose + bf16-split We (K x 512) into FRAGMENT-TILED
//     layout: short index s = ((c*64 + t)*64 + lane)*8 + j  where
//     c = n>>5, t = k>>4, lane = ((k>>3)&1)*32 + (n&31), j = k&7.
// ---------------------------------------------------------------------------
__global__ __launch_bounds__(256) void prep_kernel(
    const float* __restrict__ hidden, const float* __restrict__ W,
    const float* __restrict__ bias, float* __restrict__ hb,
    unsigned short* __restrict__ Wh, unsigned short* __restrict__ Wl)
{
    __shared__ float red[4][64];
    __shared__ float t[32][33];
    const int bx = blockIdx.x;
    if (bx < 256) {
        const int tid = threadIdx.x;
        const int h0  = (bx & 7) * 64;
        const int b   = bx >> 3;
        const int h   = h0 + (tid & 63);
        const int ks  = tid >> 6;              // 4 k-slices of 128
        const float* hrow = hidden + b * H_;
        float acc = 0.f;
        #pragma unroll 8
        for (int k = ks * 128; k < ks * 128 + 128; ++k)
            acc = fmaf(hrow[k], W[(size_t)k * H_ + h], acc);
        red[ks][tid & 63] = acc;
        __syncthreads();
        if (tid < 64)
            hb[b * H_ + h0 + tid] = red[0][tid] + red[1][tid] + red[2][tid]
                                  + red[3][tid] + bias[h0 + tid];
    } else {
        const float* We = W + (size_t)H_ * H_;   // rows [H, 3H)
        const int cx = bx - 256;                  // 0..511
        const int k0 = (cx & 31) * 32, n0 = (cx >> 5) * 32;
        const int tx = threadIdx.x & 31, ty = threadIdx.x >> 5;   // ty 0..7
        #pragma unroll
        for (int j = 0; j < 4; ++j) {
            const int k = ty + 8 * j;
            t[k][tx] = We[(size_t)(k0 + k) * H_ + n0 + tx];
        }
        __syncthreads();
        #pragma unroll
        for (int j = 0; j < 4; ++j) {
            const int n    = ty + 8 * j;
            const int ncol = n0 + n;
            const int k    = k0 + tx;
            unsigned short hi, lo;
            split_bf16(t[tx][n], hi, lo);
            const int c     = ncol >> 5;
            const int tt    = k >> 4;
            const int lane_ = ((k >> 3) & 1) * 32 + (ncol & 31);
            const size_t s  = ((size_t)(c * 64 + tt) * 64 + lane_) * 8 + (k & 7);
            Wh[s] = hi;
            Wl[s] = lo;
        }
    }
}

// ---------------------------------------------------------------------------
// Kernel 2: 256x256 MFMA GEMM, m201-style phase rhythm.
//   Round-4 post-mortem: neither pipe wall (MFMA ~768cy, LDS-read ~2300cy
//   per CU-step) explains the measured 10300cy/step -> schedule slack.
//   This round:
//   - 2 phases/K-step, each {ds_reads || stage-issues -> s_barrier ->
//     lgkmcnt(0)+sched_barrier(0) -> setprio(1) -> 24 MFMA -> setprio(0) ->
//     s_barrier}: phase p+1's LDS reads overlap phase p's MFMA drain
//     (the m196/m201-proven interleave).  Split/ds_write of A(j+1) sits in
//     phase 1's pre-barrier zone, overlapping phase 0's MFMA drain.
//   - MFMA order ks->prod->fi->fj: same-acc reuse distance 4 (was 6
//     back-to-back dependent MFMAs into one acc = latency-serialized pipe).
//     Per-acc summation order is BITWISE IDENTICAL to round 4.
//   - counted vmcnt kept (B triple-buffer, never drains to 0 in-loop).
// ---------------------------------------------------------------------------
__global__ __launch_bounds__(512, 2) void gemm_fused(
    const float* __restrict__ EO,             // (M, K) fp32
    const unsigned short* __restrict__ Bth,   // tiled (16,64,64,8) bf16 hi
    const unsigned short* __restrict__ Btl,   // tiled (16,64,64,8) bf16 lo
    const float* __restrict__ hb, const float* __restrict__ v,
    float* __restrict__ partial)              // (2, M)
{
    __shared__ unsigned short ldsA[2][2][8192];   // 64KB  [buf][hi|lo]
    __shared__ unsigned short ldsB[3][2][8192];   // 96KB  [buf][hi|lo]

    const int tid  = threadIdx.x;
    // XCD-aware decode: bid%8 = XCD; 32 blocks/XCD = 16 mt x 2 nt, nt fastest.
    const int bid  = blockIdx.x;
    const int jb   = bid >> 3;                    // 0..31
    const int mt   = (bid & 7) * 16 + (jb >> 1);  // 0..127
    const int nt   = jb & 1;                      // 0..1
    const int row0 = mt * 256;
    const int col0 = nt * 256;
    const int batch = row0 >> 10;

    const int lane   = tid & 63;
    const int wave   = tid >> 6;                  // 0..7
    const int wm     = wave >> 2, wn = wave & 3;  // 2M x 4N
    const int lane32 = lane & 31, kh = lane >> 5;

    // ---- A staging geometry: seg = tid + 512*s; m = seg>>2 (0..255); sg = seg&3.
    size_t gA[2];
    int offAw[2];
    #pragma unroll
    for (int s = 0; s < 2; ++s) {
        const int seg = tid + 512 * s;
        const int m = seg >> 2, sg = seg & 3;
        gA[s]    = (size_t)(row0 + m) * K_ + sg * 8;
        offAw[s] = ((m >> 5) * 2 + (sg >> 1)) * 512
                 + ((sg & 1) * 32 + ((m & 31) ^ sg)) * 8;
    }
    // ---- B staging (DMA): wave w stages frag slots {2w, 2w+1}.
    const unsigned short* gBh = Bth + ((size_t)(nt * 8 + wave) * 32768 + lane * 8);
    const unsigned short* gBl = Btl + ((size_t)(nt * 8 + wave) * 32768 + lane * 8);
    const int offBw = wave * 1024;                // shorts; + ks*512 per issue

    f32x16 acc[4][2];
    #pragma unroll
    for (int fi = 0; fi < 4; ++fi)
        #pragma unroll
        for (int fj = 0; fj < 2; ++fj)
            #pragma unroll
            for (int e = 0; e < 16; ++e)
                acc[fi][fj][e] = 0.f;

    // ---- prologue: A(0)->regs->split->ldsA[0]; DMA B(0)->ldsB[0], B(1)->ldsB[1]
    float4 a0[2], a1[2];
    #pragma unroll
    for (int s = 0; s < 2; ++s) {
        a0[s] = *reinterpret_cast<const float4*>(EO + gA[s]);
        a1[s] = *reinterpret_cast<const float4*>(EO + gA[s] + 4);
    }
    #pragma unroll
    for (int ks = 0; ks < 2; ++ks) {
        async_copy16(gBh + (0 + ks) * 512, &ldsB[0][0][offBw + ks * 512]);
        async_copy16(gBl + (0 + ks) * 512, &ldsB[0][1][offBw + ks * 512]);
    }
    #pragma unroll
    for (int ks = 0; ks < 2; ++ks) {
        async_copy16(gBh + (2 + ks) * 512, &ldsB[1][0][offBw + ks * 512]);
        async_copy16(gBl + (2 + ks) * 512, &ldsB[1][1][offBw + ks * 512]);
    }
    #pragma unroll
    for (int s = 0; s < 2; ++s)        // compiler auto-waits the A(0) loads
        split8_store(a0[s], a1[s], &ldsA[0][0][offAw[s]], &ldsA[0][1][offAw[s]]);
    // B(0) retired (B(1) stays in flight); own ds_writes drained before barrier.
    asm volatile("s_waitcnt vmcnt(4) lgkmcnt(0)" ::: "memory");
    __builtin_amdgcn_s_barrier();

// One phase's 24 MFMAs: ks -> prod -> f2 -> fj.  Same-acc reuse distance 4;
// per-acc order (ks0:hh,hl,lh then ks1:hh,hl,lh) identical to prior rounds.
#define PHASE_MFMA(fb)                                                         \
    _Pragma("unroll") for (int ks = 0; ks < 2; ++ks)                           \
      _Pragma("unroll") for (int p = 0; p < 3; ++p)                            \
        _Pragma("unroll") for (int f2 = 0; f2 < 2; ++f2)                       \
          _Pragma("unroll") for (int fj = 0; fj < 2; ++fj) {                   \
            acc[(fb) + f2][fj] = __builtin_amdgcn_mfma_f32_32x32x16_bf16(      \
                (p == 2) ? a_l[f2][ks] : a_h[f2][ks],                          \
                (p == 1) ? b_l[fj][ks] : b_h[fj][ks],                          \
                acc[(fb) + f2][fj], 0, 0, 0);                                  \
          }

    int bc = 0;                                   // = j % 3
    for (int j = 0; j < 32; ++j) {
        const int cur = j & 1, nxt = cur ^ 1;
        const int bn  = (bc >= 1) ? bc - 1 : 2;   // (j+2) % 3

        // ================= phase 0: B-frags + A-frags(fi 0,1) =================
        bf16x8 b_h[2][2], b_l[2][2];
        #pragma unroll
        for (int fj = 0; fj < 2; ++fj)
            #pragma unroll
            for (int ks = 0; ks < 2; ++ks) {
                const int baseB = ((wn * 2 + fj) * 2 + ks) * 512 + lane * 8;
                b_h[fj][ks] = *reinterpret_cast<const bf16x8*>(&ldsB[bc][0][baseB]);
                b_l[fj][ks] = *reinterpret_cast<const bf16x8*>(&ldsB[bc][1][baseB]);
            }
        {
            bf16x8 a_h[2][2], a_l[2][2];
            #pragma unroll
            for (int f2 = 0; f2 < 2; ++f2)
                #pragma unroll
                for (int ks = 0; ks < 2; ++ks) {
                    const int baseA = ((wm * 4 + f2) * 2 + ks) * 512
                                    + (kh * 32 + (lane32 ^ (2 * ks + kh))) * 8;
                    a_h[f2][ks] = *reinterpret_cast<const bf16x8*>(&ldsA[cur][0][baseA]);
                    a_l[f2][ks] = *reinterpret_cast<const bf16x8*>(&ldsA[cur][1][baseA]);
                }
            if (j < 31) {                         // A(j+1) -> regs (issue only)
                const int k0n = 32 * (j + 1);
                #pragma unroll
                for (int s = 0; s < 2; ++s) {
                    a0[s] = *reinterpret_cast<const float4*>(EO + gA[s] + k0n);
                    a1[s] = *reinterpret_cast<const float4*>(EO + gA[s] + k0n + 4);
                }
            }
            __builtin_amdgcn_s_barrier();
            asm volatile("s_waitcnt lgkmcnt(0)" ::: "memory");
            __builtin_amdgcn_sched_barrier(0);
            __builtin_amdgcn_s_setprio(1);
            PHASE_MFMA(0)
            __builtin_amdgcn_s_setprio(0);
            __builtin_amdgcn_s_barrier();
        }

        // ================= phase 1: A-frags(fi 2,3) + stage =================
        {
            bf16x8 a_h[2][2], a_l[2][2];
            #pragma unroll
            for (int f2 = 0; f2 < 2; ++f2)
                #pragma unroll
                for (int ks = 0; ks < 2; ++ks) {
                    const int baseA = ((wm * 4 + 2 + f2) * 2 + ks) * 512
                                    + (kh * 32 + (lane32 ^ (2 * ks + kh))) * 8;
                    a_h[f2][ks] = *reinterpret_cast<const bf16x8*>(&ldsA[cur][0][baseA]);
                    a_l[f2][ks] = *reinterpret_cast<const bf16x8*>(&ldsA[cur][1][baseA]);
                }
            if (j < 30) {                         // DMA B(j+2) -> ldsB[bn]
                const int tnxt = 2 * (j + 2);
                #pragma unroll
                for (int ks = 0; ks < 2; ++ks) {
                    async_copy16(gBh + (tnxt + ks) * 512, &ldsB[bn][0][offBw + ks * 512]);
                    async_copy16(gBl + (tnxt + ks) * 512, &ldsB[bn][1][offBw + ks * 512]);
                }
            }
            if (j < 31) {                         // split A(j+1) (auto vmcnt wait)
                #pragma unroll
                for (int s = 0; s < 2; ++s)
                    split8_store(a0[s], a1[s],
                                 &ldsA[nxt][0][offAw[s]], &ldsA[nxt][1][offAw[s]]);
            }
            __builtin_amdgcn_s_barrier();
            asm volatile("s_waitcnt lgkmcnt(0)" ::: "memory");
            __builtin_amdgcn_sched_barrier(0);
            __builtin_amdgcn_s_setprio(1);
            PHASE_MFMA(2)
            __builtin_amdgcn_s_setprio(0);
            // counted: B(j+2) DMAs (4 newest) stay in flight across the barrier
            asm volatile("s_waitcnt vmcnt(4)" ::: "memory");
            __builtin_amdgcn_s_barrier();
        }
        bc = (bc == 2) ? 0 : bc + 1;
    }
#undef PHASE_MFMA

    // ---- epilogue: tanh(acc + hb)*v, reduce over this block's 256 cols ----
    // Step 31 read ldsA[1]; red reuses ldsA[0] (disjoint).
    // 32x32 C layout: col = lane&31, row = (reg&3) + 8*(reg>>2) + 4*(lane>>5).
    const float* hb_row = hb + batch * H_;
    float hbv[2], vv[2];
    #pragma unroll
    for (int fj = 0; fj < 2; ++fj) {
        const int c = col0 + (wn * 2 + fj) * 32 + lane32;
        hbv[fj] = hb_row[c];
        vv[fj]  = v[c];
    }
    float* red = reinterpret_cast<float*>(&ldsA[0][0][0]);   // 256 rows x 4 wn
    #pragma unroll
    for (int fi = 0; fi < 4; ++fi)
        #pragma unroll
        for (int r = 0; r < 16; ++r) {
            float rs = 0.f;
            #pragma unroll
            for (int fj = 0; fj < 2; ++fj)
                rs = fmaf(fast_tanh(acc[fi][fj][r] + hbv[fj]), vv[fj], rs);
            rs += __shfl_xor(rs, 1, 64);
            rs += __shfl_xor(rs, 2, 64);
            rs += __shfl_xor(rs, 4, 64);
            rs += __shfl_xor(rs, 8, 64);
            rs += __shfl_xor(rs, 16, 64);
            if (lane32 == 0) {
                const int row = wm * 128 + fi * 32 + (r & 3) + 8 * (r >> 2) + 4 * kh;
                red[row * 4 + wn] = rs;
            }
        }
    __syncthreads();
    if (tid < 256)
        partial[(size_t)nt * M_ + row0 + tid] =
            red[tid * 4] + red[tid * 4 + 1] + red[tid * 4 + 2] + red[tid * 4 + 3];
}

// ---------------------------------------------------------------------------
// Kernel 3: per-batch softmax over S=1024 (sum of 2 partials)
// ---------------------------------------------------------------------------
__global__ __launch_bounds__(256) void softmax_kernel(
    const float* __restrict__ partial, float* __restrict__ out)
{
    const int b = blockIdx.x;
    const int tid = threadIdx.x;
    float val[4];
    float lmax = -3.0e38f;
    #pragma unroll
    for (int q = 0; q < 4; ++q) {
        const int idx = b * S_ + tid + 256 * q;
        float sum = partial[idx] + partial[M_ + idx];
        val[q] = sum;
        lmax = fmaxf(lmax, sum);
    }
    #pragma unroll
    for (int off = 32; off > 0; off >>= 1)
        lmax = fmaxf(lmax, __shfl_down(lmax, off, 64));
    __shared__ float wmax[4];
    if ((tid & 63) == 0) wmax[tid >> 6] = lmax;
    __syncthreads();
    const float gmax = fmaxf(fmaxf(wmax[0], wmax[1]), fmaxf(wmax[2], wmax[3]));
    float lsum = 0.0f;
    #pragma unroll
    for (int q = 0; q < 4; ++q) {
        val[q] = expf(val[q] - gmax);
        lsum += val[q];
    }
    #pragma unroll
    for (int off = 32; off > 0; off >>= 1)
        lsum += __shfl_down(lsum, off, 64);
    __shared__ float wsum[4];
    if ((tid & 63) == 0) wsum[tid >> 6] = lsum;
    __syncthreads();
    const float inv = 1.0f / (wsum[0] + wsum[1] + wsum[2] + wsum[3]);
    #pragma unroll
    for (int q = 0; q < 4; ++q)
        out[b * S_ + tid + 256 * q] = val[q] * inv;
}

// ---------------------------------------------------------------------------
extern "C" void kernel_launch(void* const* d_in, const int* in_sizes, int n_in,
                              void* d_out, int out_size, void* d_ws, size_t ws_size,
                              hipStream_t stream) {
    const float* hidden = (const float*)d_in[0];
    const float* EO     = (const float*)d_in[1];
    const float* W      = (const float*)d_in[2];
    const float* bias   = (const float*)d_in[3];
    const float* v      = (const float*)d_in[4];
    float* out          = (float*)d_out;

    float* hb      = (float*)d_ws;                       // 16384 floats
    float* partial = hb + B_ * H_;                       // 2*M floats used
    unsigned short* Wth = (unsigned short*)(partial + 4 * M_);
    unsigned short* Wtl = Wth + (size_t)H_ * K_;

    prep_kernel<<<768, 256, 0, stream>>>(hidden, W, bias, hb, Wth, Wtl);
    gemm_fused<<<dim3(256), 512, 0, stream>>>(EO, Wth, Wtl, hb, v, partial);
    softmax_kernel<<<B_, 256, 0, stream>>>(partial, out);
}

// Round 6
// 284.961 us; speedup vs baseline: 1.0263x; 1.0263x over previous
//
#include <hip/hip_runtime.h>
#include <math.h>

#define B_ 32
#define S_ 1024
#define H_ 512
#define K_ 1024                 // 2*H
#define M_ (B_ * S_)            // 32768

typedef __attribute__((ext_vector_type(8))) short bf16x8;
typedef __attribute__((ext_vector_type(16))) float f32x16;

// Round-half-up split: f = hi + lo.  Residual r = f - fh is EXACT regardless
// of hi's rounding mode, so half-up matches RNE accuracy (total error =
// lo rounding <= 2^-18 rel).
__device__ __forceinline__ void split_bf16(float f, unsigned short& hi, unsigned short& lo) {
    unsigned u = __float_as_uint(f);
    unsigned r = u + 0x8000u;
    hi = (unsigned short)(r >> 16);
    float fh = __uint_as_float(r & 0xffff0000u);
    float res = f - fh;
    lo = (unsigned short)((__float_as_uint(res) + 0x8000u) >> 16);
}

// split 8 floats -> two 16B LDS stores; v_perm packs 2 halves/op.
__device__ __forceinline__ void split8_store(const float4& x, const float4& y,
                                             unsigned short* hiP, unsigned short* loP) {
    float f[8] = {x.x, x.y, x.z, x.w, y.x, y.y, y.z, y.w};
    unsigned hr[8], lr[8];
    #pragma unroll
    for (int i = 0; i < 8; ++i) {
        unsigned u = __float_as_uint(f[i]);
        unsigned r = u + 0x8000u;
        hr[i] = r;
        float fh = __uint_as_float(r & 0xffff0000u);
        lr[i] = __float_as_uint(f[i] - fh) + 0x8000u;
    }
    uint4 Hv, Lv;
    Hv.x = __builtin_amdgcn_perm(hr[1], hr[0], 0x07060302u);
    Hv.y = __builtin_amdgcn_perm(hr[3], hr[2], 0x07060302u);
    Hv.z = __builtin_amdgcn_perm(hr[5], hr[4], 0x07060302u);
    Hv.w = __builtin_amdgcn_perm(hr[7], hr[6], 0x07060302u);
    Lv.x = __builtin_amdgcn_perm(lr[1], lr[0], 0x07060302u);
    Lv.y = __builtin_amdgcn_perm(lr[3], lr[2], 0x07060302u);
    Lv.z = __builtin_amdgcn_perm(lr[5], lr[4], 0x07060302u);
    Lv.w = __builtin_amdgcn_perm(lr[7], lr[6], 0x07060302u);
    *reinterpret_cast<uint4*>(hiP) = Hv;
    *reinterpret_cast<uint4*>(loP) = Lv;
}

// tanh via HW exp + rcp: (e^2x - 1)/(e^2x + 1).  ~8 ops, |err| ~1e-6.
__device__ __forceinline__ float fast_tanh(float x) {
    float xc = fminf(fmaxf(x, -15.f), 15.f);
    float t = __expf(2.0f * xc);
    return (t - 1.0f) * __builtin_amdgcn_rcpf(t + 1.0f);
}

// async 16B global -> LDS (lane i lands at lds_base + i*16; lds_base wave-uniform)
__device__ __forceinline__ void async_copy16(const void* g, void* l) {
    __builtin_amdgcn_global_load_lds(
        (const __attribute__((address_space(1))) void*)g,
        (__attribute__((address_space(3))) void*)l, 16, 0, 0);
}

// ---------------------------------------------------------------------------
// Kernel 1: merged prep.
//   blocks [0,256):  hb[b][h] = sum_k hidden[b][k]*W[k][h] + bias[h]
//   blocks [256,768): transpose + bf16-split We (K x 512) into FRAGMENT-TILED
//     layout: short index s = ((c*64 + t)*64 + lane)*8 + j  where
//     c = n>>5, t = k>>4, lane = ((k>>3)&1)*32 + (n&31), j = k&7.
// ---------------------------------------------------------------------------
__global__ __launch_bounds__(256) void prep_kernel(
    const float* __restrict__ hidden, const float* __restrict__ W,
    const float* __restrict__ bias, float* __restrict__ hb,
    unsigned short* __restrict__ Wh, unsigned short* __restrict__ Wl)
{
    __shared__ float red[4][64];
    __shared__ float t[32][33];
    const int bx = blockIdx.x;
    if (bx < 256) {
        const int tid = threadIdx.x;
        const int h0  = (bx & 7) * 64;
        const int b   = bx >> 3;
        const int h   = h0 + (tid & 63);
        const int ks  = tid >> 6;              // 4 k-slices of 128
        const float* hrow = hidden + b * H_;
        float acc = 0.f;
        #pragma unroll 8
        for (int k = ks * 128; k < ks * 128 + 128; ++k)
            acc = fmaf(hrow[k], W[(size_t)k * H_ + h], acc);
        red[ks][tid & 63] = acc;
        __syncthreads();
        if (tid < 64)
            hb[b * H_ + h0 + tid] = red[0][tid] + red[1][tid] + red[2][tid]
                                  + red[3][tid] + bias[h0 + tid];
    } else {
        const float* We = W + (size_t)H_ * H_;   // rows [H, 3H)
        const int cx = bx - 256;                  // 0..511
        const int k0 = (cx & 31) * 32, n0 = (cx >> 5) * 32;
        const int tx = threadIdx.x & 31, ty = threadIdx.x >> 5;   // ty 0..7
        #pragma unroll
        for (int j = 0; j < 4; ++j) {
            const int k = ty + 8 * j;
            t[k][tx] = We[(size_t)(k0 + k) * H_ + n0 + tx];
        }
        __syncthreads();
        #pragma unroll
        for (int j = 0; j < 4; ++j) {
            const int n    = ty + 8 * j;
            const int ncol = n0 + n;
            const int k    = k0 + tx;
            unsigned short hi, lo;
            split_bf16(t[tx][n], hi, lo);
            const int c     = ncol >> 5;
            const int tt    = k >> 4;
            const int lane_ = ((k >> 3) & 1) * 32 + (ncol & 31);
            const size_t s  = ((size_t)(c * 64 + tt) * 64 + lane_) * 8 + (k & 7);
            Wh[s] = hi;
            Wl[s] = lo;
        }
    }
}

// ---------------------------------------------------------------------------
// Kernel 2: 256x256 MFMA GEMM, 2-phase rhythm with FULL-STEP load lead.
//   r5 failure diagnosed: A(j+1) issue->consume shrank to ~300cy < L3
//   latency -> stall inside the barrier-locked zone.  This round:
//   - A reg loads DOUBLE-BUFFERED, issued one full K-step ahead (A(j+2)
//     issued at step j ph1, split+written at step j+1 ph1).  All vmcnt
//     waits are pre-satisfied in steady state.
//   - phase 0 pre-barrier = pure 16 ds_reads; phase 1 carries all staging
//     (DMA B(j+2), split A(j+1), issue A(j+2)) overlapping ph0's MFMA drain.
//   - MFMA reuse-distance 4 (ks->prod->f2->fj); per-acc order bitwise
//     identical to r4 (ks0:hh,hl,lh then ks1:...).
//   - counted vmcnt: in-loop closing wait = vmcnt(8), never 0.
// ---------------------------------------------------------------------------
__global__ __launch_bounds__(512, 2) void gemm_fused(
    const float* __restrict__ EO,             // (M, K) fp32
    const unsigned short* __restrict__ Bth,   // tiled (16,64,64,8) bf16 hi
    const unsigned short* __restrict__ Btl,   // tiled (16,64,64,8) bf16 lo
    const float* __restrict__ hb, const float* __restrict__ v,
    float* __restrict__ partial)              // (2, M)
{
    __shared__ unsigned short ldsA[2][2][8192];   // 64KB  [buf][hi|lo]
    __shared__ unsigned short ldsB[3][2][8192];   // 96KB  [buf][hi|lo]

    const int tid  = threadIdx.x;
    // XCD-aware decode: bid%8 = XCD; 32 blocks/XCD = 16 mt x 2 nt, nt fastest.
    const int bid  = blockIdx.x;
    const int jb   = bid >> 3;                    // 0..31
    const int mt   = (bid & 7) * 16 + (jb >> 1);  // 0..127
    const int nt   = jb & 1;                      // 0..1
    const int row0 = mt * 256;
    const int col0 = nt * 256;
    const int batch = row0 >> 10;

    const int lane   = tid & 63;
    const int wave   = tid >> 6;                  // 0..7
    const int wm     = wave >> 2, wn = wave & 3;  // 2M x 4N
    const int lane32 = lane & 31, kh = lane >> 5;

    // ---- A staging geometry: seg = tid + 512*s; m = seg>>2 (0..255); sg = seg&3.
    size_t gA[2];
    int offAw[2];
    #pragma unroll
    for (int s = 0; s < 2; ++s) {
        const int seg = tid + 512 * s;
        const int m = seg >> 2, sg = seg & 3;
        gA[s]    = (size_t)(row0 + m) * K_ + sg * 8;
        offAw[s] = ((m >> 5) * 2 + (sg >> 1)) * 512
                 + ((sg & 1) * 32 + ((m & 31) ^ sg)) * 8;
    }
    // ---- B staging (DMA): wave w stages frag slots {2w, 2w+1}.
    const unsigned short* gBh = Bth + ((size_t)(nt * 8 + wave) * 32768 + lane * 8);
    const unsigned short* gBl = Btl + ((size_t)(nt * 8 + wave) * 32768 + lane * 8);
    const int offBw = wave * 1024;                // shorts; + ks*512 per issue

    f32x16 acc[4][2];
    #pragma unroll
    for (int fi = 0; fi < 4; ++fi)
        #pragma unroll
        for (int fj = 0; fj < 2; ++fj)
            #pragma unroll
            for (int e = 0; e < 16; ++e)
                acc[fi][fj][e] = 0.f;

    // ---- prologue ----
    // A(0) -> setA regs -> split -> ldsA[0];  A(1) -> setB regs (held 1 step);
    // DMA B(0)->ldsB[0], B(1)->ldsB[1].
    float4 a0A[2], a1A[2], a0B[2], a1B[2];
    #pragma unroll
    for (int s = 0; s < 2; ++s) {
        a0A[s] = *reinterpret_cast<const float4*>(EO + gA[s]);
        a1A[s] = *reinterpret_cast<const float4*>(EO + gA[s] + 4);
    }
    #pragma unroll
    for (int ks = 0; ks < 2; ++ks) {
        async_copy16(gBh + (0 + ks) * 512, &ldsB[0][0][offBw + ks * 512]);
        async_copy16(gBl + (0 + ks) * 512, &ldsB[0][1][offBw + ks * 512]);
    }
    #pragma unroll
    for (int ks = 0; ks < 2; ++ks) {
        async_copy16(gBh + (2 + ks) * 512, &ldsB[1][0][offBw + ks * 512]);
        async_copy16(gBl + (2 + ks) * 512, &ldsB[1][1][offBw + ks * 512]);
    }
    #pragma unroll
    for (int s = 0; s < 2; ++s)        // compiler auto-waits the A(0) loads
        split8_store(a0A[s], a1A[s], &ldsA[0][0][offAw[s]], &ldsA[0][1][offAw[s]]);
    #pragma unroll
    for (int s = 0; s < 2; ++s) {      // issue A(1) (consumed at step 0 ph1)
        a0B[s] = *reinterpret_cast<const float4*>(EO + gA[s] + 32);
        a1B[s] = *reinterpret_cast<const float4*>(EO + gA[s] + 32 + 4);
    }
    // retire B(0) DMAs (4 oldest); B(1)+A(1) stay in flight across the barrier.
    asm volatile("s_waitcnt vmcnt(8) lgkmcnt(0)" ::: "memory");
    __builtin_amdgcn_s_barrier();

// One phase's 24 MFMAs: ks -> prod -> f2 -> fj.  Same-acc reuse distance 4;
// per-acc order (ks0:hh,hl,lh then ks1:hh,hl,lh) identical to prior rounds.
#define PHASE_MFMA(fb)                                                         \
    _Pragma("unroll") for (int ks = 0; ks < 2; ++ks)                           \
      _Pragma("unroll") for (int p = 0; p < 3; ++p)                            \
        _Pragma("unroll") for (int f2 = 0; f2 < 2; ++f2)                       \
          _Pragma("unroll") for (int fj = 0; fj < 2; ++fj) {                   \
            acc[(fb) + f2][fj] = __builtin_amdgcn_mfma_f32_32x32x16_bf16(      \
                (p == 2) ? a_l[f2][ks] : a_h[f2][ks],                          \
                (p == 1) ? b_l[fj][ks] : b_h[fj][ks],                          \
                acc[(fb) + f2][fj], 0, 0, 0);                                  \
          }

// One K-step.  CUR compile-time (unroll-2).  S0/S1 = reg set holding A(J+1)
// (issued a FULL step ago); I0/I1 = reg set to receive A(J+2).
#define K_STEP(J, CUR, S0, S1, I0, I1)                                         \
  {                                                                            \
    const int nxt = (CUR) ^ 1;                                                 \
    const int bn  = (bc >= 1) ? bc - 1 : 2;      /* (J+2) % 3 */               \
    /* ---------- phase 0: pure ds_reads, then MFMA fi 0,1 ---------- */       \
    bf16x8 b_h[2][2], b_l[2][2];                                               \
    _Pragma("unroll") for (int fj = 0; fj < 2; ++fj)                           \
      _Pragma("unroll") for (int ks = 0; ks < 2; ++ks) {                       \
        const int baseB = ((wn * 2 + fj) * 2 + ks) * 512 + lane * 8;           \
        b_h[fj][ks] = *reinterpret_cast<const bf16x8*>(&ldsB[bc][0][baseB]);   \
        b_l[fj][ks] = *reinterpret_cast<const bf16x8*>(&ldsB[bc][1][baseB]);   \
      }                                                                        \
    {                                                                          \
      bf16x8 a_h[2][2], a_l[2][2];                                             \
      _Pragma("unroll") for (int f2 = 0; f2 < 2; ++f2)                         \
        _Pragma("unroll") for (int ks = 0; ks < 2; ++ks) {                     \
          const int baseA = ((wm * 4 + f2) * 2 + ks) * 512                     \
                          + (kh * 32 + (lane32 ^ (2 * ks + kh))) * 8;          \
          a_h[f2][ks] = *reinterpret_cast<const bf16x8*>(&ldsA[CUR][0][baseA]);\
          a_l[f2][ks] = *reinterpret_cast<const bf16x8*>(&ldsA[CUR][1][baseA]);\
        }                                                                      \
      __builtin_amdgcn_s_barrier();                                            \
      asm volatile("s_waitcnt lgkmcnt(0)" ::: "memory");                       \
      __builtin_amdgcn_sched_barrier(0);                                       \
      __builtin_amdgcn_s_setprio(1);                                           \
      PHASE_MFMA(0)                                                            \
      __builtin_amdgcn_s_setprio(0);                                           \
      __builtin_amdgcn_s_barrier();                                            \
    }                                                                          \
    /* ---------- phase 1: ds_reads + ALL staging, then MFMA fi 2,3 ----- */   \
    {                                                                          \
      bf16x8 a_h[2][2], a_l[2][2];                                             \
      _Pragma("unroll") for (int f2 = 0; f2 < 2; ++f2)                         \
        _Pragma("unroll") for (int ks = 0; ks < 2; ++ks) {                     \
          const int baseA = ((wm * 4 + 2 + f2) * 2 + ks) * 512                 \
                          + (kh * 32 + (lane32 ^ (2 * ks + kh))) * 8;          \
          a_h[f2][ks] = *reinterpret_cast<const bf16x8*>(&ldsA[CUR][0][baseA]);\
          a_l[f2][ks] = *reinterpret_cast<const bf16x8*>(&ldsA[CUR][1][baseA]);\
        }                                                                      \
      if ((J) < 30) {                            /* DMA B(J+2) -> ldsB[bn] */  \
        const int tnxt = 2 * ((J) + 2);                                        \
        _Pragma("unroll") for (int ks = 0; ks < 2; ++ks) {                     \
          async_copy16(gBh + (tnxt + ks) * 512, &ldsB[bn][0][offBw + ks*512]); \
          async_copy16(gBl + (tnxt + ks) * 512, &ldsB[bn][1][offBw + ks*512]); \
        }                                                                      \
      }                                                                        \
      if ((J) < 31) {       /* split A(J+1): loads issued a FULL step ago */   \
        _Pragma("unroll") for (int s = 0; s < 2; ++s)                          \
          split8_store(S0[s], S1[s],                                           \
                       &ldsA[nxt][0][offAw[s]], &ldsA[nxt][1][offAw[s]]);      \
      }                                                                        \
      if ((J) < 30) {                            /* issue A(J+2) */            \
        const int k0n = 32 * ((J) + 2);                                        \
        _Pragma("unroll") for (int s = 0; s < 2; ++s) {                        \
          I0[s] = *reinterpret_cast<const float4*>(EO + gA[s] + k0n);          \
          I1[s] = *reinterpret_cast<const float4*>(EO + gA[s] + k0n + 4);      \
        }                                                                      \
      }                                                                        \
      __builtin_amdgcn_s_barrier();                                            \
      asm volatile("s_waitcnt lgkmcnt(0)" ::: "memory");                       \
      __builtin_amdgcn_sched_barrier(0);                                       \
      __builtin_amdgcn_s_setprio(1);                                           \
      PHASE_MFMA(2)                                                            \
      __builtin_amdgcn_s_setprio(0);                                           \
      if ((J) < 30) { asm volatile("s_waitcnt vmcnt(8)" ::: "memory"); }       \
      else          { asm volatile("s_waitcnt vmcnt(0)" ::: "memory"); }       \
      __builtin_amdgcn_s_barrier();                                            \
    }                                                                          \
    bc = (bc == 2) ? 0 : bc + 1;                                               \
  }

    int bc = 0;                                   // = j % 3
    #pragma unroll 1
    for (int jj = 0; jj < 16; ++jj) {
        const int je = 2 * jj;
        // even step: split consumes setB (A(je+1)), issues into setA (A(je+2))
        K_STEP(je,     0, a0B, a1B, a0A, a1A)
        // odd step: split consumes setA, issues into setB
        K_STEP(je + 1, 1, a0A, a1A, a0B, a1B)
    }
#undef K_STEP
#undef PHASE_MFMA

    // ---- epilogue: tanh(acc + hb)*v, reduce over this block's 256 cols ----
    // Step 31 read ldsA[1]; red reuses ldsA[0] (disjoint).
    // 32x32 C layout: col = lane&31, row = (reg&3) + 8*(reg>>2) + 4*(lane>>5).
    const float* hb_row = hb + batch * H_;
    float hbv[2], vv[2];
    #pragma unroll
    for (int fj = 0; fj < 2; ++fj) {
        const int c = col0 + (wn * 2 + fj) * 32 + lane32;
        hbv[fj] = hb_row[c];
        vv[fj]  = v[c];
    }
    float* red = reinterpret_cast<float*>(&ldsA[0][0][0]);   // 256 rows x 4 wn
    #pragma unroll
    for (int fi = 0; fi < 4; ++fi)
        #pragma unroll
        for (int r = 0; r < 16; ++r) {
            float rs = 0.f;
            #pragma unroll
            for (int fj = 0; fj < 2; ++fj)
                rs = fmaf(fast_tanh(acc[fi][fj][r] + hbv[fj]), vv[fj], rs);
            rs += __shfl_xor(rs, 1, 64);
            rs += __shfl_xor(rs, 2, 64);
            rs += __shfl_xor(rs, 4, 64);
            rs += __shfl_xor(rs, 8, 64);
            rs += __shfl_xor(rs, 16, 64);
            if (lane32 == 0) {
                const int row = wm * 128 + fi * 32 + (r & 3) + 8 * (r >> 2) + 4 * kh;
                red[row * 4 + wn] = rs;
            }
        }
    __syncthreads();
    if (tid < 256)
        partial[(size_t)nt * M_ + row0 + tid] =
            red[tid * 4] + red[tid * 4 + 1] + red[tid * 4 + 2] + red[tid * 4 + 3];
}

// ---------------------------------------------------------------------------
// Kernel 3: per-batch softmax over S=1024 (sum of 2 partials)
// ---------------------------------------------------------------------------
__global__ __launch_bounds__(256) void softmax_kernel(
    const float* __restrict__ partial, float* __restrict__ out)
{
    const int b = blockIdx.x;
    const int tid = threadIdx.x;
    float val[4];
    float lmax = -3.0e38f;
    #pragma unroll
    for (int q = 0; q < 4; ++q) {
        const int idx = b * S_ + tid + 256 * q;
        float sum = partial[idx] + partial[M_ + idx];
        val[q] = sum;
        lmax = fmaxf(lmax, sum);
    }
    #pragma unroll
    for (int off = 32; off > 0; off >>= 1)
        lmax = fmaxf(lmax, __shfl_down(lmax, off, 64));
    __shared__ float wmax[4];
    if ((tid & 63) == 0) wmax[tid >> 6] = lmax;
    __syncthreads();
    const float gmax = fmaxf(fmaxf(wmax[0], wmax[1]), fmaxf(wmax[2], wmax[3]));
    float lsum = 0.0f;
    #pragma unroll
    for (int q = 0; q < 4; ++q) {
        val[q] = expf(val[q] - gmax);
        lsum += val[q];
    }
    #pragma unroll
    for (int off = 32; off > 0; off >>= 1)
        lsum += __shfl_down(lsum, off, 64);
    __shared__ float wsum[4];
    if ((tid & 63) == 0) wsum[tid >> 6] = lsum;
    __syncthreads();
    const float inv = 1.0f / (wsum[0] + wsum[1] + wsum[2] + wsum[3]);
    #pragma unroll
    for (int q = 0; q < 4; ++q)
        out[b * S_ + tid + 256 * q] = val[q] * inv;
}

// ---------------------------------------------------------------------------
extern "C" void kernel_launch(void* const* d_in, const int* in_sizes, int n_in,
                              void* d_out, int out_size, void* d_ws, size_t ws_size,
                              hipStream_t stream) {
    const float* hidden = (const float*)d_in[0];
    const float* EO     = (const float*)d_in[1];
    const float* W      = (const float*)d_in[2];
    const float* bias   = (const float*)d_in[3];
    const float* v      = (const float*)d_in[4];
    float* out          = (float*)d_out;

    float* hb      = (float*)d_ws;                       // 16384 floats
    float* partial = hb + B_ * H_;                       // 2*M floats used
    unsigned short* Wth = (unsigned short*)(partial + 4 * M_);
    unsigned short* Wtl = Wth + (size_t)H_ * K_;

    prep_kernel<<<768, 256, 0, stream>>>(hidden, W, bias, hb, Wth, Wtl);
    gemm_fused<<<dim3(256), 512, 0, stream>>>(EO, Wth, Wtl, hb, v, partial);
    softmax_kernel<<<B_, 256, 0, stream>>>(partial, out);
}